// Round 8
// baseline (131.800 us; speedup 1.0000x reference)
//
#include <hip/hip_runtime.h>

// QRNN fo-pool: B=8, C=256, H=256, T=4096, K=2
// PX (x -> xq single-tap frag-packed bf16, zero pad frag-row at tf=0)
// PW (W -> aq frag-packed [hs][gate][hlf], 16 k-steps incl. both taps)
// G  (MFMA GEMM 192x128, 4 waves, wave tile 96x64 (6mx4n), BK=128 4 phases,
//     gl16 staging (tap-0 via per-lane shifted global addresses);
//     fused epilogue: z,f -> LDS -> chunk=32 scan -> c_local fp32 + cumprod bf16,
//     aggregates, o bf16 direct)
// S2 (aggregate scan -> carry_in), S3 (elementwise c = cl + P*carry; h = o*c)

typedef unsigned short ushort_t;
typedef __attribute__((ext_vector_type(8))) short short8_t;
typedef __attribute__((ext_vector_type(4))) float f32x4;

#define B_ 8
#define C_ 256
#define H_ 256
#define T_ 4096
#define TCH 32
#define NCH 128
#define LZP 129   // scan LDS pad: bank = (h + t) % 32 across 64 h-lanes -> 2-way (free)
#define NTF 257   // frag-rows per (b): 1 zero row + 256

__device__ __forceinline__ unsigned short f2bf(float f) {
  unsigned int u = __float_as_uint(f);
  u += 0x7fffu + ((u >> 16) & 1u);
  return (unsigned short)(u >> 16);
}
__device__ __forceinline__ float bf2f(unsigned short u) {
  return __uint_as_float(((unsigned int)u) << 16);
}
__device__ __forceinline__ float sigm(float v) { return 1.f / (1.f + __expf(-v)); }
__device__ __forceinline__ float tanh_f(float v) { return 2.f / (1.f + __expf(-2.f * v)) - 1.f; }

__device__ __forceinline__ void gl16(const ushort_t* g, ushort_t* l) {
  __builtin_amdgcn_global_load_lds(
      (const __attribute__((address_space(1))) unsigned int*)g,
      (__attribute__((address_space(3))) unsigned int*)l, 16, 0, 0);
}

// ---------------- PX: x [B][C][T] f32 -> xq single-tap frag-packed bf16 ------------------
// xq[((b*NTF + 1 + tf)*8 + ks)*512 + lane*8 + j] = bf16(x[b][32ks + (lane>>4)*8 + j][16tf + (lane&15)])
// frag-row tf_store=0 is zeros (t = -16..-1 pad for the shifted tap-0 reads).
__global__ __launch_bounds__(256) void qrnn_pack_x(const float* __restrict__ x,
                                                   ushort_t* __restrict__ xq) {
  __shared__ float tile[32][129];
  const int tid = threadIdx.x;
  const int t0 = blockIdx.x * 128, c0 = blockIdx.y * 32, b = blockIdx.z;
#pragma unroll
  for (int p = 0; p < 4; ++p) {
    const int j = tid + p * 256;        // 1024 float4 slots
    const int row = j >> 5, q = j & 31;
    float4 v = *reinterpret_cast<const float4*>(x + ((size_t)(b * C_ + c0 + row)) * T_ + t0 + q * 4);
    tile[row][q * 4 + 0] = v.x; tile[row][q * 4 + 1] = v.y;
    tile[row][q * 4 + 2] = v.z; tile[row][q * 4 + 3] = v.w;
  }
  const int ks0 = c0 >> 5;
  if (blockIdx.x == 0 && tid < 64) {    // zero pad frag-row (tf_store = 0)
    uint4 zz = make_uint4(0, 0, 0, 0);
    *reinterpret_cast<uint4*>(xq + ((size_t)(b * NTF) * 8 + ks0) * 512 + tid * 8) = zz;
  }
  __syncthreads();
#pragma unroll
  for (int q2 = 0; q2 < 2; ++q2) {
    const int p = tid + q2 * 256;       // 512 (tfl,lane) pairs
    const int tfl = p >> 6, lane = p & 63;
    const int l15 = lane & 15, g8 = (lane >> 4) * 8;
    const int tcol = tfl * 16 + l15;
    ushort_t o0[8];
#pragma unroll
    for (int j = 0; j < 8; ++j) o0[j] = f2bf(tile[g8 + j][tcol]);
    ushort_t* d0 = xq + ((size_t)(b * NTF + 1 + (t0 >> 4) + tfl) * 8 + ks0) * 512 + lane * 8;
    *reinterpret_cast<uint4*>(d0) = *reinterpret_cast<uint4*>(&o0[0]);
  }
}

// ---------------- PW: W -> aq frag-packed, mf = hs*12 + g*4 + hlf, 16 ks ----------------
__global__ __launch_bounds__(256) void qrnn_pack_w(const float* __restrict__ Wz,
                                                   const float* __restrict__ Wf,
                                                   const float* __restrict__ Wo,
                                                   ushort_t* __restrict__ aq) {
  const int idx = blockIdx.x * 256 + threadIdx.x;   // < 48*16*64
  const int lane = idx & 63;
  const int ks = (idx >> 6) & 15;
  const int mf = idx >> 10;            // 0..47
  const int hs = mf / 12, rem = mf % 12;
  const int g = rem >> 2, hlf = rem & 3;
  const int h = hs * 64 + hlf * 16 + (lane & 15);
  const float* W = (g == 0) ? Wz : ((g == 1) ? Wf : Wo);
  ushort_t o[8];
#pragma unroll
  for (int j = 0; j < 8; ++j) {
    const int k = ks * 32 + (lane >> 4) * 8 + j;
    const int c = k & 255;
    const int tap = (k < 256) ? 1 : 0;
    o[j] = f2bf(W[((size_t)h * C_ + c) * 2 + tap]);
  }
  *reinterpret_cast<uint4*>(aq + (size_t)idx * 8) = *reinterpret_cast<uint4*>(&o[0]);
}

// ---------------- G: MFMA GEMM 192m x 128t, 4 waves (6mx4n), 4 phases of BK=128 ----------
__global__ __launch_bounds__(256, 2) void qrnn_g(const ushort_t* __restrict__ aq,
                                                 const ushort_t* __restrict__ xq,
                                                 const float* __restrict__ bz,
                                                 const float* __restrict__ bfv,
                                                 const float* __restrict__ bo,
                                                 float* __restrict__ cl,
                                                 ushort_t* __restrict__ pb,
                                                 ushort_t* __restrict__ ob,
                                                 float* __restrict__ aggP,
                                                 float* __restrict__ aggC) {
  __shared__ __align__(16) char ldsu[81920];        // staging: A 48KB + B 32KB; epi 66KB alias
  ushort_t* As = (ushort_t*)ldsu;                   // [row = mfl*4+ksl][lane][8]  (48 rows)
  ushort_t* Bs = (ushort_t*)(ldsu + 49152);         // [row = tfl*4+ksl][lane][8]  (32 rows)
  float* lz = (float*)ldsu;                         // [64][LZP]  (z -> c_local)
  float* lf = (float*)(ldsu + 33024);               // [64][LZP]  (f -> cumprod)

  const int tid = threadIdx.x;
  const int lane = tid & 63;
  const int w = tid >> 6;                           // wave 0..3
  const int wm = w >> 1, wt = w & 1;
  const int l15 = lane & 15, g4 = lane >> 4;
  const int bid = blockIdx.x;
  const int b = bid & 7;                            // XCD-local batch
  const int hs = (bid >> 3) & 3;
  const int tt = bid >> 5;

  // tap-0 per-lane source shift: lane l15==0 reaches back one frag-row, lane+15
  const int sh0 = (l15 == 0) ? 1 : 0;
  const int lane0 = lane + (sh0 ? 15 : -1);

  f32x4 acc[6][4];
#pragma unroll
  for (int i = 0; i < 6; ++i)
#pragma unroll
    for (int n = 0; n < 4; ++n) acc[i][n] = (f32x4){0.f, 0.f, 0.f, 0.f};

  for (int p = 0; p < 4; ++p) {
    // ---- stage: wave w handles rows [20w, 20w+20) of 48 A-rows + 32 B-rows ----
#pragma unroll
    for (int rr = 0; rr < 20; ++rr) {
      const int row = w * 20 + rr;
      if (row < 48) {
        const int mfl = row >> 2, ksl = row & 3;
        const int kg = p * 4 + ksl;
        gl16(aq + (((size_t)(hs * 12 + mfl) * 16 + kg) << 9) + lane * 8, As + row * 512);
      } else {
        const int rb = row - 48;
        const int tfl = rb >> 2, ksl = rb & 3;
        const int kg = p * 4 + ksl;
        if (kg < 8) {       // tap 1: x[t]
          gl16(xq + (((size_t)(b * NTF + 1 + tt * 8 + tfl) * 8 + kg) << 9) + lane * 8,
               Bs + rb * 512);
        } else {            // tap 0: x[t-1] via shifted lane/frag-row
          gl16(xq + (((size_t)(b * NTF + 1 + tt * 8 + tfl - sh0) * 8 + (kg - 8)) << 9) + lane0 * 8,
               Bs + rb * 512);
        }
      }
    }
    __syncthreads();
    // ---- compute: 4 ksl x (10 ds_read_b128 + 24 MFMA) per wave ----
#pragma unroll
    for (int l = 0; l < 4; ++l) {
      short8_t a[6], bb[4];
#pragma unroll
      for (int i = 0; i < 6; ++i)
        a[i] = *reinterpret_cast<const short8_t*>(&As[(size_t)(((wm * 6 + i) * 4 + l) * 64 + lane) * 8]);
#pragma unroll
      for (int n = 0; n < 4; ++n)
        bb[n] = *reinterpret_cast<const short8_t*>(&Bs[(size_t)(((wt * 4 + n) * 4 + l) * 64 + lane) * 8]);
#pragma unroll
      for (int i = 0; i < 6; ++i)
#pragma unroll
        for (int n = 0; n < 4; ++n)
          acc[i][n] = __builtin_amdgcn_mfma_f32_16x16x32_bf16(a[i], bb[n], acc[i][n], 0, 0, 0);
    }
    __syncthreads();
  }

  // ---- epilogue phase 1: bias+act; z,f -> LDS; o -> global bf16 ----
#pragma unroll
  for (int i = 0; i < 6; ++i) {
    const int mfl = wm * 6 + i;          // 0..11
    const int g = mfl >> 2;              // 0=z 1=f 2=o
    const int hl0 = (mfl & 3) * 16;
    const float* bias = (g == 0) ? bz : ((g == 1) ? bfv : bo);
#pragma unroll
    for (int r = 0; r < 4; ++r) {
      const int hl = hl0 + g4 * 4 + r;                 // C/D: row=(lane>>4)*4+reg
      const float bvv = bias[hs * 64 + hl];
#pragma unroll
      for (int n = 0; n < 4; ++n) {
        const int tl = (wt * 4 + n) * 16 + l15;        // C/D: col=lane&15
        const float v = acc[i][n][r] + bvv;
        if (g == 0)      lz[hl * LZP + tl] = tanh_f(v);
        else if (g == 1) lf[hl * LZP + tl] = sigm(v);
        else ob[((size_t)b * H_ + hs * 64 + hl) * T_ + tt * 128 + tl] = f2bf(sigm(v));
      }
    }
  }
  __syncthreads();

  // ---- phase 2: in-LDS chunk=32 scan (256 threads: h = tid&63, chunk = tid>>6) ----
  {
    const int h = tid & 63, ch = tid >> 6;
    float* pz = lz + h * LZP + ch * 32;
    float* pf = lf + h * LZP + ch * 32;
    float c = 0.f, pcp = 1.f;
#pragma unroll
    for (int t = 0; t < TCH; ++t) {
      const float f = pf[t], z = pz[t];
      c = f * (c - z) + z;
      pcp *= f;
      pz[t] = c;               // c_local
      pf[t] = pcp;             // cumprod
    }
    const int chunkg = tt * 4 + ch;
    aggP[((size_t)b * NCH + chunkg) * H_ + hs * 64 + h] = pcp;
    aggC[((size_t)b * NCH + chunkg) * H_ + hs * 64 + h] = c;
  }
  __syncthreads();

  // ---- phase 3: coalesced write-out: c_local fp32, cumprod bf16 ----
  float* clb = cl + ((size_t)b * H_ + hs * 64) * T_ + tt * 128;
  ushort_t* pbb = pb + ((size_t)b * H_ + hs * 64) * T_ + tt * 128;
#pragma unroll
  for (int q = 0; q < 8; ++q) {
    const int j = tid + q * 256;         // 2048 float4 units over [64][128]
    const int row = j >> 5, col = (j & 31) * 4;
    float4 v = make_float4(lz[row * LZP + col], lz[row * LZP + col + 1],
                           lz[row * LZP + col + 2], lz[row * LZP + col + 3]);
    *reinterpret_cast<float4*>(clb + (size_t)row * T_ + col) = v;
  }
#pragma unroll
  for (int q = 0; q < 8; ++q) {
    const int j = tid + q * 256;         // 2048 float4-reads -> uint2 (4 bf16) stores
    const int row = j >> 5, col = (j & 31) * 4;
    ushort_t o4[4];
    o4[0] = f2bf(lf[row * LZP + col]);     o4[1] = f2bf(lf[row * LZP + col + 1]);
    o4[2] = f2bf(lf[row * LZP + col + 2]); o4[3] = f2bf(lf[row * LZP + col + 3]);
    *reinterpret_cast<uint2*>(pbb + (size_t)row * T_ + col) = *reinterpret_cast<uint2*>(&o4[0]);
  }
}

// ---------------- S2: scan over chunk aggregates -> carry_in -----------------------------
__global__ __launch_bounds__(256) void qrnn_s2(const float* __restrict__ aggP,
                                               const float* __restrict__ aggC,
                                               float* __restrict__ cin) {
  const int b = blockIdx.x, h = threadIdx.x;
  float carry = 0.f;
  for (int jb = 0; jb < NCH; jb += 8) {
    float P[8], Cv[8];
#pragma unroll
    for (int u = 0; u < 8; ++u) {
      P[u] = aggP[((size_t)b * NCH + jb + u) * H_ + h];
      Cv[u] = aggC[((size_t)b * NCH + jb + u) * H_ + h];
    }
#pragma unroll
    for (int u = 0; u < 8; ++u) {
      cin[((size_t)b * NCH + jb + u) * H_ + h] = carry;
      carry = Cv[u] + P[u] * carry;
    }
  }
}

// ---------------- S3: elementwise c = cl + P*carry; h = o*c ------------------------------
__global__ __launch_bounds__(256) void qrnn_s3(const float* __restrict__ cl,
                                               const ushort_t* __restrict__ pb,
                                               const ushort_t* __restrict__ ob,
                                               const float* __restrict__ cin,
                                               float* __restrict__ outc,
                                               float* __restrict__ outh) {
  const int n4 = B_ * H_ * T_ / 4;
  for (int i4 = blockIdx.x * 256 + threadIdx.x; i4 < n4; i4 += gridDim.x * 256) {
    const int idx = i4 << 2;
    const int t = idx & (T_ - 1);
    const int bh = idx >> 12;
    const float carry = cin[((size_t)(bh >> 8) * NCH + (t >> 5)) * H_ + (bh & 255)];
    float4 clv = reinterpret_cast<const float4*>(cl)[i4];
    uint2 pv = reinterpret_cast<const uint2*>(pb)[i4];
    uint2 ov = reinterpret_cast<const uint2*>(ob)[i4];
    const float c0 = clv.x + bf2f((ushort_t)(pv.x & 0xffff)) * carry;
    const float c1 = clv.y + bf2f((ushort_t)(pv.x >> 16)) * carry;
    const float c2 = clv.z + bf2f((ushort_t)(pv.y & 0xffff)) * carry;
    const float c3 = clv.w + bf2f((ushort_t)(pv.y >> 16)) * carry;
    float4 cv = make_float4(c0, c1, c2, c3);
    float4 hv = make_float4(bf2f((ushort_t)(ov.x & 0xffff)) * c0,
                            bf2f((ushort_t)(ov.x >> 16)) * c1,
                            bf2f((ushort_t)(ov.y & 0xffff)) * c2,
                            bf2f((ushort_t)(ov.y >> 16)) * c3);
    reinterpret_cast<float4*>(outc)[i4] = cv;
    reinterpret_cast<float4*>(outh)[i4] = hv;
  }
}

extern "C" void kernel_launch(void* const* d_in, const int* in_sizes, int n_in,
                              void* d_out, int out_size, void* d_ws, size_t ws_size,
                              hipStream_t stream) {
  const float* x  = (const float*)d_in[0];
  const float* Wz = (const float*)d_in[1];
  const float* bz = (const float*)d_in[2];
  const float* Wf = (const float*)d_in[3];
  const float* bfv= (const float*)d_in[4];
  const float* Wo = (const float*)d_in[5];
  const float* bo = (const float*)d_in[6];

  float* outh = (float*)d_out;                        // [B][H][T]
  float* outc = outh + (size_t)B_ * H_ * T_;          // [B][H][T]

  constexpr size_t XQ_OFF  = 0;                       // 8*257*8*512*2 = 16,842,752
  constexpr size_t AQ_OFF  = 16842752;                //    786,432
  constexpr size_t CL_OFF  = 17629184;                // 33,554,432 (c_local fp32)
  constexpr size_t PB_OFF  = 51183616;                // 16,777,216 (cumprod bf16)
  constexpr size_t OB_OFF  = 67960832;                // 16,777,216 (o bf16)
  constexpr size_t AGP_OFF = 84738048;                //  1,048,576
  constexpr size_t AGC_OFF = 85786624;                //  1,048,576
  constexpr size_t CIN_OFF = 86835200;                //  1,048,576
  constexpr size_t WS_NEED = 87883776;
  if (ws_size < WS_NEED) return;

  ushort_t* xq = (ushort_t*)((char*)d_ws + XQ_OFF);
  ushort_t* aq = (ushort_t*)((char*)d_ws + AQ_OFF);
  float* clb   = (float*)((char*)d_ws + CL_OFF);
  ushort_t* pbb= (ushort_t*)((char*)d_ws + PB_OFF);
  ushort_t* ob = (ushort_t*)((char*)d_ws + OB_OFF);
  float* aggP  = (float*)((char*)d_ws + AGP_OFF);
  float* aggC  = (float*)((char*)d_ws + AGC_OFF);
  float* cin   = (float*)((char*)d_ws + CIN_OFF);

  qrnn_pack_x<<<dim3(T_ / 128, C_ / 32, B_), 256, 0, stream>>>(x, xq);
  qrnn_pack_w<<<dim3(192), 256, 0, stream>>>(Wz, Wf, Wo, aq);
  qrnn_g<<<dim3(1024), 256, 0, stream>>>(aq, xq, bz, bfv, bo, clb, pbb, ob, aggP, aggC);
  qrnn_s2<<<dim3(B_), 256, 0, stream>>>(aggP, aggC, cin);
  qrnn_s3<<<dim3(2048), 256, 0, stream>>>(clb, pbb, ob, cin, outc, outh);
}